// Round 6
// baseline (703.324 us; speedup 1.0000x reference)
//
#include <hip/hip_runtime.h>
#include <hip/hip_bf16.h>

#define H 1024
#define B 32
#define S 2048

typedef __attribute__((ext_vector_type(8))) short bf16x8;
typedef __attribute__((ext_vector_type(4))) float f32x4;

union U4 { uint4 u; bf16x8 b; };

__device__ __forceinline__ unsigned short f2bf(float f) {
    unsigned u = __float_as_uint(f);
    unsigned r = (u + 0x7fffu + ((u >> 16) & 1u)) >> 16;
    return (unsigned short)r;
}

// pack two fp32 -> one dword of two bf16 (lo=a, hi=b)
__device__ __forceinline__ unsigned pk2(float a, float b) {
#if __has_builtin(__builtin_amdgcn_cvt_pk_bf16_f32)
    typedef __attribute__((ext_vector_type(2))) __bf16 bfp2;
    union { bfp2 v; unsigned u; } p;
    p.v = __builtin_amdgcn_cvt_pk_bf16_f32(a, b);
    return p.u;
#else
    // round-half-up + byte-perm: 3 VALU
    unsigned ua = __float_as_uint(a) + 0x8000u;
    unsigned ub = __float_as_uint(b) + 0x8000u;
    return __builtin_amdgcn_perm(ub, ua, 0x07060302u);
#endif
}

__device__ __forceinline__ uint4 pack8(float4 x, float4 y) {
    uint4 p;
    p.x = pk2(x.x, x.y);
    p.y = pk2(x.z, x.w);
    p.z = pk2(y.x, y.y);
    p.w = pk2(y.z, y.w);
    return p;
}

// RNE pack for the weight pre-pass (exactness not critical either way)
__device__ __forceinline__ uint4 pack8_rne(float4 x, float4 y) {
    uint4 p;
    p.x = (unsigned)f2bf(x.x) | ((unsigned)f2bf(x.y) << 16);
    p.y = (unsigned)f2bf(x.z) | ((unsigned)f2bf(x.w) << 16);
    p.z = (unsigned)f2bf(y.x) | ((unsigned)f2bf(y.y) << 16);
    p.w = (unsigned)f2bf(y.z) | ((unsigned)f2bf(y.w) << 16);
    return p;
}

__device__ __forceinline__ float ftanh(float x) {
    float x2 = __builtin_amdgcn_fmed3f(x + x, -30.f, 30.f);
    float e = __expf(x2);
    return 1.f - 2.f * __builtin_amdgcn_rcpf(e + 1.f);
}

// ---------------------------------------------------------------------------
// K0: Ua_w fp32 [n][k] -> bf16 MFMA-B-frag order: UaSw[nb(8)][kc(32)][nt(8)*64+lane]
__global__ void k0_swizzle(const float* __restrict__ Ua, uint4* __restrict__ UaSw) {
    int t = blockIdx.x * 256 + threadIdx.x;   // 0..131071
    int lane = t & 63;
    int nt = (t >> 6) & 7;
    int kc = (t >> 9) & 31;
    int nb = t >> 14;
    int n = nb * 128 + nt * 16 + (lane & 15);
    int k = kc * 32 + ((lane >> 4) & 3) * 8;
    const float4* src = (const float4*)(Ua + (size_t)n * H + k);
    UaSw[t] = pack8_rne(src[0], src[1]);
}

// ---------------------------------------------------------------------------
// K1: qp[b][n] = sum_h query[b][h]*Wa_w[n][h] + Wa_b[n] + Ua_b[n]
__global__ __launch_bounds__(256) void k1_qproj(
    const float* __restrict__ q, const float* __restrict__ Wa,
    const float* __restrict__ Wab, const float* __restrict__ Uab,
    float* __restrict__ qp) {
    int b = blockIdx.y;
    int t = threadIdx.x;
    int n = blockIdx.x * 64 + (t >> 2);
    int quarter = t & 3;
    __shared__ float qs[H];
    for (int i = t; i < H; i += 256) qs[i] = q[b * H + i];
    __syncthreads();
    const float4* wr = (const float4*)(Wa + (size_t)n * H + quarter * 256);
    const float* qq = qs + quarter * 256;
    float acc = 0.f;
#pragma unroll 4
    for (int i = 0; i < 64; i++) {
        float4 w = wr[i];
        acc += qq[i * 4 + 0] * w.x + qq[i * 4 + 1] * w.y +
               qq[i * 4 + 2] * w.z + qq[i * 4 + 3] * w.w;
    }
    acc += __shfl_xor(acc, 1, 64);
    acc += __shfl_xor(acc, 2, 64);
    if (quarter == 0) qp[b * H + n] = acc + Wab[n] + Uab[n];
}

// ---------------------------------------------------------------------------
// K2v4: barrier-free streaming GEMM, wave tile 64x128 (4 m-tiles x 8 n-tiles).
// Block = 256 rows x 128 n (one nb). A loaded fp32 from keys (prefetched one
// kc ahead) and packed in-register via v_cvt_pk_bf16_f32; B bf16 pre-swizzled,
// loaded JIT (L2-hot). No LDS, no barriers in the K-loop.
__global__ __launch_bounds__(256, 2) void k2_scores3(
    const float* __restrict__ keys, const uint4* __restrict__ UaSw,
    const float* __restrict__ qp, const float* __restrict__ Vaw,
    float* __restrict__ sp) {
    const int tid = threadIdx.x;
    const int lane = tid & 63;
    const int wm = tid >> 6;         // wave 0..3 : rows wm*64..+64
    const int lid = blockIdx.x;      // 0..2047
    const int c = lid & 7;           // XCD slot (round-robin by linear id)
    const int qx = lid >> 3;
    const int nb = qx & 7;           // nb cycles fastest within an XCD
    const int mblk = (qx >> 3) * 8 + c;   // 0..255
    const int b = mblk >> 3;
    const int s0 = (mblk & 7) << 8;  // 256-row block

    const int colq = (lane >> 4) & 3;     // quad 0..3
    const float4* pa[4];
#pragma unroll
    for (int mt = 0; mt < 4; mt++) {
        int row = s0 + wm * 64 + mt * 16 + (lane & 15);
        pa[mt] = (const float4*)(keys + ((size_t)b * S + row) * H) + colq * 2;
    }
    const uint4* pb = UaSw + (size_t)nb * 16384 + lane;

    f32x4 acc[4][8];
#pragma unroll
    for (int mt = 0; mt < 4; mt++)
#pragma unroll
        for (int nt = 0; nt < 8; nt++) acc[mt][nt] = (f32x4){0.f, 0.f, 0.f, 0.f};

    // prologue: A fp32 for kc=0
    float4 xf[4], yf[4];
#pragma unroll
    for (int mt = 0; mt < 4; mt++) { xf[mt] = pa[mt][0]; yf[mt] = pa[mt][1]; }

    for (int kc = 0; kc < 32; kc++) {
        // B frags JIT (first consumer is ~40 VALU later; waitcnt fine-grained)
        U4 bfr[8];
#pragma unroll
        for (int nt = 0; nt < 8; nt++) bfr[nt].u = pb[kc * 512 + nt * 64];
        // pack A for this kc (waits on last iteration's A loads)
        U4 a[4];
#pragma unroll
        for (int mt = 0; mt < 4; mt++) a[mt].u = pack8(xf[mt], yf[mt]);
        // prefetch A fp32 for kc+1
        if (kc < 31) {
#pragma unroll
            for (int mt = 0; mt < 4; mt++) {
                xf[mt] = pa[mt][(kc + 1) * 8];
                yf[mt] = pa[mt][(kc + 1) * 8 + 1];
            }
        }
#pragma unroll
        for (int nt = 0; nt < 8; nt++)
#pragma unroll
            for (int mt = 0; mt < 4; mt++)
                acc[mt][nt] = __builtin_amdgcn_mfma_f32_16x16x32_bf16(
                    a[mt].b, bfr[nt].b, acc[mt][nt], 0, 0, 0);
    }

    // epilogue: tanh, dot Va, shfl-reduce over col(16), float4 store (disjoint)
    const int col = lane & 15, qd = lane >> 4;
    float qv[8], vv[8];
#pragma unroll
    for (int nt = 0; nt < 8; nt++) {
        int n = nb * 128 + nt * 16 + col;
        qv[nt] = qp[b * H + n];
        vv[nt] = Vaw[n];
    }
#pragma unroll
    for (int mt = 0; mt < 4; mt++) {
        float rs[4] = {0.f, 0.f, 0.f, 0.f};
#pragma unroll
        for (int nt = 0; nt < 8; nt++)
#pragma unroll
            for (int r = 0; r < 4; r++)
                rs[r] += ftanh(acc[mt][nt][r] + qv[nt]) * vv[nt];
#pragma unroll
        for (int r = 0; r < 4; r++) {
            float v = rs[r];
            v += __shfl_xor(v, 1, 64);
            v += __shfl_xor(v, 2, 64);
            v += __shfl_xor(v, 4, 64);
            v += __shfl_xor(v, 8, 64);
            rs[r] = v;
        }
        if (col == 0) {
            float4 st = {rs[0], rs[1], rs[2], rs[3]};
            *(float4*)&sp[(size_t)nb * B * S + b * S + s0 + wm * 64 + mt * 16 + qd * 4] = st;
        }
    }
}

// ---------------------------------------------------------------------------
// K4: fused partial-sum + softmax + weights-write + context partial.
// grid (32,32): block (sc,b) owns 64 s-rows; stats recomputed per block.
__global__ __launch_bounds__(256) void k4_ctx(const float* __restrict__ keys,
                                              const float* __restrict__ sp,
                                              float* __restrict__ out) {
    int sc = blockIdx.x, b = blockIdx.y;
    int t = threadIdx.x;
    __shared__ float red[256];
    __shared__ float wl[64];

    float v[8];
#pragma unroll
    for (int i = 0; i < 8; i++) {
        int s = i * 256 + t;
        float sum = 0.f;
#pragma unroll
        for (int nb = 0; nb < 8; nb++) sum += sp[(size_t)nb * B * S + b * S + s];
        v[i] = sum;
    }
    float lm = -1e30f;
#pragma unroll
    for (int i = 0; i < 8; i++) lm = fmaxf(lm, v[i]);
    red[t] = lm;
    __syncthreads();
    for (int s = 128; s > 0; s >>= 1) {
        if (t < s) red[t] = fmaxf(red[t], red[t + s]);
        __syncthreads();
    }
    float m = red[0];
    __syncthreads();
    float ls = 0.f;
#pragma unroll
    for (int i = 0; i < 8; i++) ls += __expf(v[i] - m);
    red[t] = ls;
    __syncthreads();
    for (int s = 128; s > 0; s >>= 1) {
        if (t < s) red[t] += red[t + s];
        __syncthreads();
    }
    float inv = 1.f / red[0];

    if (t < 64) {
        int s = sc * 64 + t;
        float sum = 0.f;
#pragma unroll
        for (int nb = 0; nb < 8; nb++) sum += sp[(size_t)nb * B * S + b * S + s];
        float w = __expf(sum - m) * inv;
        wl[t] = w;
        out[B * H + b * S + s] = w;
    }
    __syncthreads();

    const float4* kp = (const float4*)(keys + ((size_t)b * S + sc * 64) * H) + t;
    float4 acc = {0.f, 0.f, 0.f, 0.f};
#pragma unroll 8
    for (int s = 0; s < 64; s++) {
        float4 kv = kp[(size_t)s * 256];
        float w = wl[s];
        acc.x += w * kv.x; acc.y += w * kv.y;
        acc.z += w * kv.z; acc.w += w * kv.w;
    }
    float* dst = out + b * H + t * 4;
    atomicAdd(dst + 0, acc.x);
    atomicAdd(dst + 1, acc.y);
    atomicAdd(dst + 2, acc.z);
    atomicAdd(dst + 3, acc.w);
}

// ---------------------------------------------------------------------------
extern "C" void kernel_launch(void* const* d_in, const int* in_sizes, int n_in,
                              void* d_out, int out_size, void* d_ws, size_t ws_size,
                              hipStream_t stream) {
    const float* query = (const float*)d_in[0];
    const float* keys  = (const float*)d_in[1];
    const float* Wa_w  = (const float*)d_in[2];
    const float* Wa_b  = (const float*)d_in[3];
    const float* Ua_w  = (const float*)d_in[4];
    const float* Ua_b  = (const float*)d_in[5];
    const float* Va_w  = (const float*)d_in[6];
    float* out = (float*)d_out;

    // ws: [0,2MB) UaSw; [2MB,+128KB) qp; [2MB+128KB,+2MB) sp[8][B][S]
    uint4* UaSw = (uint4*)d_ws;
    float* qp = (float*)((char*)d_ws + (2u << 20));
    float* sp = (float*)((char*)d_ws + (2u << 20) + (128u << 10));

    hipMemsetAsync(d_out, 0, B * H * sizeof(float), stream);  // context acc

    k0_swizzle<<<512, 256, 0, stream>>>(Ua_w, UaSw);
    k1_qproj<<<dim3(16, B), 256, 0, stream>>>(query, Wa_w, Wa_b, Ua_b, qp);
    k2_scores3<<<2048, 256, 0, stream>>>(keys, UaSw, qp, Va_w, sp);
    k4_ctx<<<dim3(32, B), 256, 0, stream>>>(keys, sp, out);
}